// Round 6
// baseline (765.672 us; speedup 1.0000x reference)
//
#include <hip/hip_runtime.h>
#include <hip/hip_bf16.h>

#define NCELL 100000
#define NGENE 8000
#define DIM   128
#define NE_CG 1500000
#define NE_GC 1500000
#define NE_CC 1000000
#define NE_GG 200000
#define SLOPE 0.05f
#define LN_EPS 1e-5f

typedef __attribute__((ext_vector_type(8))) short bf16x8;
typedef __attribute__((ext_vector_type(4))) float f32x4;

__device__ __forceinline__ float bflo(unsigned v) { return __uint_as_float(v << 16); }
__device__ __forceinline__ float bfhi(unsigned v) { return __uint_as_float(v & 0xffff0000u); }
__device__ __forceinline__ unsigned short f2bf(float x) {
    union { float f; unsigned u; } a; a.f = x;
    unsigned r = a.u + 0x7fffu + ((a.u >> 16) & 1u);   // round-to-nearest-even
    return (unsigned short)(r >> 16);
}
__device__ __forceinline__ unsigned pack2(float x, float y) {
    return (unsigned)f2bf(x) | ((unsigned)f2bf(y) << 16);
}

// ---------------- fused f32 -> bf16 conversion (cell then gene) ----------------
__global__ __launch_bounds__(256)
void conv2_k(const float* __restrict__ inc, unsigned short* __restrict__ outc,
             const float* __restrict__ ing, unsigned short* __restrict__ outg,
             int cellBlocks, int n2c, int n2g) {
    const float* in; unsigned short* out; int i, n2;
    if ((int)blockIdx.x < cellBlocks) {
        in = inc; out = outc; n2 = n2c; i = blockIdx.x * 256 + threadIdx.x;
    } else {
        in = ing; out = outg; n2 = n2g; i = (blockIdx.x - cellBlocks) * 256 + threadIdx.x;
    }
    if (i < n2) {
        float2 v = ((const float2*)in)[i];
        ((unsigned*)out)[i] = pack2(v.x, v.y);
    }
}

// ---------------- fused weight pack: [W1;W2] -> MFMA B-frag layout ----------------
__global__ void pack2_w_k(const float* __restrict__ WAc, const float* __restrict__ WBc,
                          unsigned short* __restrict__ Wpc,
                          const float* __restrict__ WAg, const float* __restrict__ WBg,
                          unsigned short* __restrict__ Wpg) {
    int bb = blockIdx.x;
    const float *WA, *WB; unsigned short* Wp;
    if (bb < 64) { WA = WAc; WB = WBc; Wp = Wpc; }
    else { bb -= 64; WA = WAg; WB = WBg; Wp = Wpg; }
    int lane = threadIdx.x;   // 64
    int t = bb >> 3, c = bb & 7;
    int n = t * 16 + (lane & 15);
    int k0 = c * 32 + (lane >> 4) * 8;
    #pragma unroll
    for (int j = 0; j < 8; ++j) {
        int k = k0 + j;
        float x = (k < 128) ? WA[k * 128 + n] : WB[(k - 128) * 128 + n];
        Wp[((size_t)(bb * 64 + lane)) * 8 + j] = f2bf(x);
    }
}

// ================= binned CSR build, fixed-capacity bins =================
struct RelP {
    const int* src; const int* dst; int n; int shift;
    int nbins; int N; int cap;
    int* deg; int* offg; int* bkt;
    int* bcur; unsigned* stg;
    int cblk0;   // first block id in fill grid
    int sblk0;   // first block id in csr grid
};

__global__ __launch_bounds__(256)
void bin_fill4_k(RelP r0, RelP r1, RelP r2, RelP r3) {
    int b = blockIdx.x;
    RelP R = (b >= r3.cblk0) ? r3 : (b >= r2.cblk0) ? r2 : (b >= r1.cblk0) ? r1 : r0;
    int lb = b - R.cblk0;
    __shared__ int cnt[512];
    __shared__ int basem[512];
    int tid = threadIdx.x;
    cnt[tid] = 0; cnt[tid + 256] = 0;
    __syncthreads();
    int base = lb * 4096;
    int bins[16]; int ranks[16]; unsigned pk[16];
    #pragma unroll
    for (int it = 0; it < 16; ++it) {
        int i = base + it * 256 + tid;
        bins[it] = -1;
        if (i < R.n) {
            int d = R.dst[i];
            int bn = d >> R.shift;
            int dl = d & ((1 << R.shift) - 1);
            bins[it] = bn;
            pk[it] = (unsigned)R.src[i] | ((unsigned)dl << 20);
            ranks[it] = atomicAdd(&cnt[bn], 1);
        }
    }
    __syncthreads();
    if (cnt[tid])       basem[tid]       = atomicAdd(&R.bcur[tid],       cnt[tid]);
    if (cnt[tid + 256]) basem[tid + 256] = atomicAdd(&R.bcur[tid + 256], cnt[tid + 256]);
    __syncthreads();
    #pragma unroll
    for (int it = 0; it < 16; ++it)
        if (bins[it] >= 0) {
            int r = basem[bins[it]] + ranks[it];
            if (r >= R.cap) r = R.cap - 1;           // paranoia clamp (stays in own bin)
            R.stg[(size_t)bins[it] * R.cap + r] = pk[it];
        }
}

__global__ __launch_bounds__(256)
void bin_csr4_k(RelP r0, RelP r1, RelP r2, RelP r3) {
    int b = blockIdx.x;
    RelP R = (b >= r3.sblk0) ? r3 : (b >= r2.sblk0) ? r2 : (b >= r1.sblk0) ? r1 : r0;
    int lb = b - R.sblk0;
    int tid = threadIdx.x;
    int ebase = lb * R.cap;
    int cnt = R.bcur[lb]; if (cnt > R.cap) cnt = R.cap;
    __shared__ int degm[256];
    __shared__ int sc[256];
    __shared__ int cur[256];
    degm[tid] = 0;
    __syncthreads();
    for (int i = tid; i < cnt; i += 256)
        atomicAdd(&degm[(R.stg[ebase + i] >> 20) & 255], 1);
    __syncthreads();
    int x = degm[tid];
    sc[tid] = x;
    __syncthreads();
    for (int ofs = 1; ofs < 256; ofs <<= 1) {
        int t = (tid >= ofs) ? sc[tid - ofs] : 0;
        __syncthreads();
        sc[tid] += t;
        __syncthreads();
    }
    int excl = sc[tid] - x;
    cur[tid] = excl;
    int node = (lb << R.shift) + tid;
    if (tid < (1 << R.shift) && node < R.N) { R.deg[node] = x; R.offg[node] = ebase + excl; }
    __syncthreads();
    for (int i = tid; i < cnt; i += 256) {
        unsigned p = R.stg[ebase + i];
        int dl = (p >> 20) & 255;
        int r = atomicAdd(&cur[dl], 1);
        R.bkt[ebase + r] = (int)(p & 0xFFFFFu);
    }
}

// ---------------- gather v3: one node per 16-lane GROUP (4 nodes/wave) -----------------
// Group g owns node wbase+g entirely; lane c holds channels 8c..8c+7. No cross-lane
// reduction needed. 4 prologue chains (off/deg->bkt->row) run in parallel per wave.
__global__ __launch_bounds__(256)
void gather3_k(const unsigned short* __restrict__ hc, const unsigned short* __restrict__ hg,
               const int* __restrict__ off_gc, const int* __restrict__ deg_gc, const int* __restrict__ bkt_gc,
               const int* __restrict__ off_cc, const int* __restrict__ deg_cc, const int* __restrict__ bkt_cc,
               const int* __restrict__ off_cg, const int* __restrict__ deg_cg, const int* __restrict__ bkt_cg,
               const int* __restrict__ off_gg, const int* __restrict__ deg_gg, const int* __restrict__ bkt_gg,
               unsigned short* __restrict__ Acat_c, unsigned short* __restrict__ Acat_g,
               int cellBlocks) {
    int wave = threadIdx.x >> 6, lane = threadIdx.x & 63;
    int g = lane >> 4, c = lane & 15;
    const unsigned char *hA, *hB;
    const int *offA, *degA, *bktA, *offB, *degB, *bktB;
    unsigned short* Aout; int node, N;
    if ((int)blockIdx.x < cellBlocks) {
        node = (blockIdx.x * 4 + wave) * 4 + g; N = NCELL;
        hA = (const unsigned char*)hg; offA = off_gc; degA = deg_gc; bktA = bkt_gc;
        hB = (const unsigned char*)hc; offB = off_cc; degB = deg_cc; bktB = bkt_cc;
        Aout = Acat_c;
    } else {
        node = ((blockIdx.x - cellBlocks) * 4 + wave) * 4 + g; N = NGENE;
        hA = (const unsigned char*)hc; offA = off_cg; degA = deg_cg; bktA = bkt_cg;
        hB = (const unsigned char*)hg; offB = off_gg; degB = deg_gg; bktB = bkt_gg;
        Aout = Acat_g;
    }
    bool valid = node < N;
    int nodeC = valid ? node : N - 1;
    int nA = valid ? degA[nodeC] : 0;
    int nB = valid ? degB[nodeC] : 0;
    int sA = offA[nodeC];
    int sB = offB[nodeC];

    // wave-uniform trip count = max over the 4 groups
    int mx = (nA > nB) ? nA : nB;
    mx = max(mx, __shfl_xor(mx, 16));
    mx = max(mx, __shfl_xor(mx, 32));

    float aA[8] = {0.f, 0.f, 0.f, 0.f, 0.f, 0.f, 0.f, 0.f};
    float aB[8] = {0.f, 0.f, 0.f, 0.f, 0.f, 0.f, 0.f, 0.f};
    unsigned coff = (unsigned)c << 4;

    #pragma unroll 4
    for (int j = 0; j < mx; ++j) {
        if (j < nA) {
            unsigned off = ((unsigned)bktA[sA + j] << 8) + coff;
            uint4 v = *(const uint4*)(hA + off);
            aA[0] += bflo(v.x); aA[1] += bfhi(v.x);
            aA[2] += bflo(v.y); aA[3] += bfhi(v.y);
            aA[4] += bflo(v.z); aA[5] += bfhi(v.z);
            aA[6] += bflo(v.w); aA[7] += bfhi(v.w);
        }
        if (j < nB) {
            unsigned off = ((unsigned)bktB[sB + j] << 8) + coff;
            uint4 v = *(const uint4*)(hB + off);
            aB[0] += bflo(v.x); aB[1] += bfhi(v.x);
            aB[2] += bflo(v.y); aB[3] += bfhi(v.y);
            aB[4] += bflo(v.z); aB[5] += bfhi(v.z);
            aB[6] += bflo(v.w); aB[7] += bfhi(v.w);
        }
    }
    if (valid) {
        float invA = 1.0f / fmaxf((float)nA, 1.0f);
        float invB = 1.0f / fmaxf((float)nB, 1.0f);
        uint4* rowp = (uint4*)(Aout + (size_t)node * 256);
        rowp[c] = make_uint4(pack2(aA[0] * invA, aA[1] * invA), pack2(aA[2] * invA, aA[3] * invA),
                             pack2(aA[4] * invA, aA[5] * invA), pack2(aA[6] * invA, aA[7] * invA));
        rowp[16 + c] = make_uint4(pack2(aB[0] * invB, aB[1] * invB), pack2(aB[2] * invB, aB[3] * invB),
                                  pack2(aB[4] * invB, aB[5] * invB), pack2(aB[6] * invB, aB[7] * invB));
    }
}

// ---------------- fused MFMA GEMM + bias + LeakyReLU + LN (cell & gene) ----------------
#define GBM 128
__global__ __launch_bounds__(256)
void gemm2_ln_k(const unsigned short* __restrict__ Acat_c, const unsigned short* __restrict__ Acat_g,
                const unsigned short* __restrict__ Wp_c, const unsigned short* __restrict__ Wp_g,
                const float* __restrict__ bias_c, const float* __restrict__ bias_g,
                const float* __restrict__ ls_c, const float* __restrict__ lb_c,
                const float* __restrict__ ls_g, const float* __restrict__ lb_g,
                unsigned short* __restrict__ outh_c, unsigned short* __restrict__ outh_g,
                float* __restrict__ outf_c, float* __restrict__ outf_g,
                int cellBlocks) {
    const unsigned short *A, *Wp; const float *bias, *lns, *lnb;
    unsigned short* outh; float* outf; int M, mb;
    if ((int)blockIdx.x < cellBlocks) {
        A = Acat_c; Wp = Wp_c; bias = bias_c; lns = ls_c; lnb = lb_c;
        outh = outh_c; outf = outf_c; M = NCELL; mb = blockIdx.x;
    } else {
        A = Acat_g; Wp = Wp_g; bias = bias_g; lns = ls_g; lnb = lb_g;
        outh = outh_g; outf = outf_g; M = NGENE; mb = blockIdx.x - cellBlocks;
    }
    __shared__ unsigned short Ws[32768];  // 64 KB
    int tid = threadIdx.x;
    {
        const uint4* s = (const uint4*)Wp;
        uint4* d = (uint4*)Ws;
        #pragma unroll
        for (int i = tid; i < 4096; i += 256) d[i] = s[i];
    }
    __syncthreads();

    int wave = tid >> 6, lane = tid & 63;
    int col0 = lane & 15;
    int kq = lane >> 4;
    int m_base = mb * GBM + wave * 32;

    f32x4 acc[2][8];
    #pragma unroll
    for (int mt = 0; mt < 2; ++mt)
        #pragma unroll
        for (int t = 0; t < 8; ++t) acc[mt][t] = (f32x4){0.f, 0.f, 0.f, 0.f};

    const unsigned short* Ar0 = A + (size_t)(m_base + col0) * 256 + kq * 8;
    const unsigned short* Ar1 = Ar0 + 16 * 256;
    #pragma unroll
    for (int c = 0; c < 8; ++c) {
        bf16x8 a0 = *(const bf16x8*)(Ar0 + c * 32);
        bf16x8 a1 = *(const bf16x8*)(Ar1 + c * 32);
        #pragma unroll
        for (int t = 0; t < 8; ++t) {
            bf16x8 b = *(const bf16x8*)(Ws + ((t * 8 + c) * 64 + lane) * 8);
            acc[0][t] = __builtin_amdgcn_mfma_f32_16x16x32_bf16(a0, b, acc[0][t], 0, 0, 0);
            acc[1][t] = __builtin_amdgcn_mfma_f32_16x16x32_bf16(a1, b, acc[1][t], 0, 0, 0);
        }
    }

    float bias_r[8], s_r[8], b_r[8];
    #pragma unroll
    for (int t = 0; t < 8; ++t) {
        int col = t * 16 + col0;
        bias_r[t] = bias[col]; s_r[t] = lns[col]; b_r[t] = lnb[col];
    }
    #pragma unroll
    for (int mt = 0; mt < 2; ++mt) {
        #pragma unroll
        for (int r = 0; r < 4; ++r) {
            int row = m_base + mt * 16 + kq * 4 + r;
            float v[8]; float sum = 0.f, sq = 0.f;
            #pragma unroll
            for (int t = 0; t < 8; ++t) {
                float x = acc[mt][t][r] + bias_r[t];
                x = (x >= 0.f) ? x : SLOPE * x;
                v[t] = x; sum += x; sq += x * x;
            }
            #pragma unroll
            for (int ofs = 1; ofs <= 8; ofs <<= 1) {
                sum += __shfl_xor(sum, ofs);
                sq  += __shfl_xor(sq, ofs);
            }
            float mu = sum * (1.0f / 128.0f);
            float var = sq * (1.0f / 128.0f) - mu * mu;
            float rstd = rsqrtf(var + LN_EPS);
            if (row < M) {
                if (outh) {
                    #pragma unroll
                    for (int t = 0; t < 8; ++t)
                        outh[(size_t)row * 128 + t * 16 + col0] =
                            f2bf((v[t] - mu) * rstd * s_r[t] + b_r[t]);
                } else {
                    #pragma unroll
                    for (int t = 0; t < 8; ++t)
                        outf[(size_t)row * 128 + t * 16 + col0] =
                            (v[t] - mu) * rstd * s_r[t] + b_r[t];
                }
            }
        }
    }
}

extern "C" void kernel_launch(void* const* d_in, const int* in_sizes, int n_in,
                              void* d_out, int out_size, void* d_ws, size_t ws_size,
                              hipStream_t stream) {
    const float* h_cell = (const float*)d_in[0];
    const float* h_gene = (const float*)d_in[1];
    const int* src_cg = (const int*)d_in[2];
    const int* dst_cg = (const int*)d_in[3];
    const int* src_gc = (const int*)d_in[4];
    const int* dst_gc = (const int*)d_in[5];
    const int* src_cc = (const int*)d_in[6];
    const int* dst_cc = (const int*)d_in[7];
    const int* src_gg = (const int*)d_in[8];
    const int* dst_gg = (const int*)d_in[9];
    const float* W_cg = (const float*)d_in[10];
    const float* W_gc = (const float*)d_in[11];
    const float* W_cc = (const float*)d_in[12];
    const float* W_gg = (const float*)d_in[13];
    const float* b_cell = (const float*)d_in[14];
    const float* b_gene = (const float*)d_in[15];
    const float* ln_s_cell = (const float*)d_in[16];
    const float* ln_b_cell = (const float*)d_in[17];
    const float* ln_s_gene = (const float*)d_in[18];
    const float* ln_b_gene = (const float*)d_in[19];
    float* out = (float*)d_out;

    const int MPC = ((NCELL + GBM - 1) / GBM) * GBM;
    const int MPG = ((NGENE + GBM - 1) / GBM) * GBM;
    const int NB_C = (NCELL + 255) / 256;   // 391 bins (shift 8)
    const int NB_G = (NGENE + 15) / 16;     // 500 bins (shift 4)
    // fixed bin capacities: mean + >8 sigma (Poisson)
    const int CAP_GC = 4352;   // mean 3836
    const int CAP_CC = 3072;   // mean 2558
    const int CAP_CG = 3584;   // mean 3000
    const int CAP_GG = 768;    // mean 400

    char* wsb = (char*)d_ws;
    size_t off = 0;
    auto alloc = [&](size_t bytes) -> char* {
        char* p = wsb + off;
        off = (off + bytes + 255) & ~(size_t)255;
        return p;
    };
    unsigned short* Acat_c = (unsigned short*)alloc((size_t)MPC * 256 * 2);
    unsigned short* Acat_g = (unsigned short*)alloc((size_t)MPG * 256 * 2);
    unsigned short* hcb0 = (unsigned short*)alloc((size_t)NCELL * DIM * 2);
    unsigned short* hgb0 = (unsigned short*)alloc((size_t)NGENE * DIM * 2);
    unsigned short* hcb1 = (unsigned short*)alloc((size_t)NCELL * DIM * 2);
    unsigned short* hgb1 = (unsigned short*)alloc((size_t)NGENE * DIM * 2);
    unsigned short* Wp_cell = (unsigned short*)alloc(65536);
    unsigned short* Wp_gene = (unsigned short*)alloc(65536);
    int ndeg = 2 * NCELL + 2 * NGENE;
    int* degs = (int*)alloc((size_t)ndeg * 4);
    int* deg_gc = degs;
    int* deg_cc = degs + NCELL;
    int* deg_cg = degs + 2 * NCELL;
    int* deg_gg = degs + 2 * NCELL + NGENE;
    int* offs = (int*)alloc((size_t)ndeg * 4);
    int* off_gc = offs;
    int* off_cc = offs + NCELL;
    int* off_cg = offs + 2 * NCELL;
    int* off_gg = offs + 2 * NCELL + NGENE;
    int* bkt_gc = (int*)alloc((size_t)NB_C * CAP_GC * 4);
    int* bkt_cc = (int*)alloc((size_t)NB_C * CAP_CC * 4);
    int* bkt_cg = (int*)alloc((size_t)NB_G * CAP_CG * 4);
    int* bkt_gg = (int*)alloc((size_t)NB_G * CAP_GG * 4);
    unsigned* stg_gc = (unsigned*)alloc((size_t)NB_C * CAP_GC * 4);
    unsigned* stg_cc = (unsigned*)alloc((size_t)NB_C * CAP_CC * 4);
    unsigned* stg_cg = (unsigned*)alloc((size_t)NB_G * CAP_CG * 4);
    unsigned* stg_gg = (unsigned*)alloc((size_t)NB_G * CAP_GG * 4);
    int* binmem = (int*)alloc(4 * 512 * 4);

    // ---- input conversion + weight packing (fused) ----
    const int n2c = NCELL * DIM / 2, n2g = NGENE * DIM / 2;
    const int convCB = (n2c + 255) / 256;
    const int convGB = (n2g + 255) / 256;
    conv2_k<<<convCB + convGB, 256, 0, stream>>>(h_cell, hcb0, h_gene, hgb0, convCB, n2c, n2g);
    pack2_w_k<<<128, 64, 0, stream>>>(W_gc, W_cc, Wp_cell, W_cg, W_gg, Wp_gene);

    // ---- binned CSR build: fill (fixed-cap bins) + per-bin counting sort ----
    hipMemsetAsync(binmem, 0, 4 * 512 * 4, stream);
    const int nbk_gc = (NE_GC + 4095) / 4096;
    const int nbk_cc = (NE_CC + 4095) / 4096;
    const int nbk_cg = (NE_CG + 4095) / 4096;
    const int nbk_gg = (NE_GG + 4095) / 4096;
    auto mkrel = [&](const int* s, const int* d, int n, int shift, int nbins, int N, int cap,
                     int* deg, int* offg, int* bkt, int* bm, unsigned* stg,
                     int cblk0, int sblk0) {
        RelP r;
        r.src = s; r.dst = d; r.n = n; r.shift = shift; r.nbins = nbins; r.N = N; r.cap = cap;
        r.deg = deg; r.offg = offg; r.bkt = bkt;
        r.bcur = bm; r.stg = stg;
        r.cblk0 = cblk0; r.sblk0 = sblk0;
        return r;
    };
    RelP r0 = mkrel(src_gc, dst_gc, NE_GC, 8, NB_C, NCELL, CAP_GC, deg_gc, off_gc, bkt_gc,
                    binmem + 0 * 512, stg_gc, 0, 0);
    RelP r1 = mkrel(src_cc, dst_cc, NE_CC, 8, NB_C, NCELL, CAP_CC, deg_cc, off_cc, bkt_cc,
                    binmem + 1 * 512, stg_cc, nbk_gc, NB_C);
    RelP r2 = mkrel(src_cg, dst_cg, NE_CG, 4, NB_G, NGENE, CAP_CG, deg_cg, off_cg, bkt_cg,
                    binmem + 2 * 512, stg_cg, nbk_gc + nbk_cc, 2 * NB_C);
    RelP r3 = mkrel(src_gg, dst_gg, NE_GG, 4, NB_G, NGENE, CAP_GG, deg_gg, off_gg, bkt_gg,
                    binmem + 3 * 512, stg_gg, nbk_gc + nbk_cc + nbk_cg, 2 * NB_C + NB_G);
    const int cntBlocks = nbk_gc + nbk_cc + nbk_cg + nbk_gg;
    const int csrBlocks = 2 * NB_C + 2 * NB_G;
    bin_fill4_k<<<cntBlocks, 256, 0, stream>>>(r0, r1, r2, r3);
    bin_csr4_k<<<csrBlocks, 256, 0, stream>>>(r0, r1, r2, r3);

    // ---- two shared layers ----
    const int gatherCB = NCELL / 16;              // 6250 blocks (16 nodes each)
    const int gatherGB = (NGENE + 15) / 16;       // 500 blocks
    const int gemmCB = MPC / GBM;                 // 782
    const int gemmGB = MPG / GBM;                 // 63
    const unsigned short* hc = hcb0;
    const unsigned short* hg = hgb0;
    for (int layer = 0; layer < 2; ++layer) {
        int final_ = (layer == 1);
        gather3_k<<<gatherCB + gatherGB, 256, 0, stream>>>(
            hc, hg,
            off_gc, deg_gc, bkt_gc, off_cc, deg_cc, bkt_cc,
            off_cg, deg_cg, bkt_cg, off_gg, deg_gg, bkt_gg,
            Acat_c, Acat_g, gatherCB);
        gemm2_ln_k<<<gemmCB + gemmGB, 256, 0, stream>>>(
            Acat_c, Acat_g, Wp_cell, Wp_gene, b_cell, b_gene,
            ln_s_cell, ln_b_cell, ln_s_gene, ln_b_gene,
            final_ ? nullptr : hcb1, final_ ? nullptr : hgb1,
            final_ ? out : nullptr, final_ ? out + (size_t)NCELL * DIM : nullptr,
            gemmCB);
        hc = hcb1;
        hg = hgb1;
    }
}